// Round 15
// baseline (649.683 us; speedup 1.0000x reference)
//
#include <hip/hip_runtime.h>
#include <hip/hip_fp16.h>

#define WG 256
#define NBIN 512

typedef _Float16 f16;
typedef f16 f16x8 __attribute__((ext_vector_type(8)));
typedef float f32x4 __attribute__((ext_vector_type(4)));

// ---- fp16 helpers: 4 channels <-> uint2 ----
__device__ __forceinline__ float4 h4_to_f4(uint2 u) {
    union { unsigned int x; __half2 h; } a, b;
    a.x = u.x; b.x = u.y;
    float2 f0 = __half22float2(a.h);
    float2 f1 = __half22float2(b.h);
    return make_float4(f0.x, f0.y, f1.x, f1.y);
}
__device__ __forceinline__ uint2 f4_to_h4(float4 v) {
    union { unsigned int x; __half2 h; } a, b;
    a.h = __floats2half2_rn(v.x, v.y);
    b.h = __floats2half2_rn(v.z, v.w);
    return make_uint2(a.x, b.x);
}

// ---------------- setup kernels ----------------

__global__ void k_zero(int* __restrict__ a, int n) {
    int i = blockIdx.x * blockDim.x + threadIdx.x;
    if (i < n) a[i] = 0;
}

__global__ void k_count(const int* __restrict__ dst, int* __restrict__ deg, int E) {
    int e = blockIdx.x * blockDim.x + threadIdx.x;
    if (e < E) atomicAdd(&deg[dst[e]], 1);
}

__global__ void k_dis(const int* __restrict__ deg, float* __restrict__ dis, int N) {
    int n = blockIdx.x * blockDim.x + threadIdx.x;
    if (n < N) {
        int d = deg[n];
        dis[n] = (d > 0) ? rsqrtf((float)d) : 0.0f;
    }
}

// ---- degree histogram -> counting sort -> nodeof permutation (wave load balance) ----
__global__ void k_hist(const int* __restrict__ deg, int* __restrict__ hist, int N) {
    int n = blockIdx.x * blockDim.x + threadIdx.x;
    if (n < N) atomicAdd(&hist[min(deg[n], NBIN - 1)], 1);
}

__global__ __launch_bounds__(NBIN) void k_scan_hist(const int* __restrict__ hist,
                                                    int* __restrict__ hstart) {
    __shared__ int s[NBIN];
    int t = threadIdx.x;
    int v = hist[t];
    s[t] = v;
    __syncthreads();
    for (int off = 1; off < NBIN; off <<= 1) {
        int u = (t >= off) ? s[t - off] : 0;
        __syncthreads();
        s[t] += u;
        __syncthreads();
    }
    hstart[t] = s[t] - v;   // exclusive
}

__global__ void k_place(const int* __restrict__ deg, const int* __restrict__ hstart,
                        int* __restrict__ hfill, int* __restrict__ nodeof, int N) {
    int n = blockIdx.x * blockDim.x + threadIdx.x;
    if (n >= N) return;
    int key = min(deg[n], NBIN - 1);
    int pos = hstart[key] + atomicAdd(&hfill[key], 1);
    nodeof[pos] = n;
}

// ---- hierarchical scan (rowptr) ----
__global__ __launch_bounds__(1024) void k_scan_blk(const int* __restrict__ deg,
                                                   int* __restrict__ rowptr,
                                                   int* __restrict__ bsum, int N) {
    __shared__ int s[1024];
    int t = threadIdx.x;
    int gid = blockIdx.x * 1024 + t;
    int v = (gid < N) ? deg[gid] : 0;
    s[t] = v;
    __syncthreads();
    for (int off = 1; off < 1024; off <<= 1) {
        int u = (t >= off) ? s[t - off] : 0;
        __syncthreads();
        s[t] += u;
        __syncthreads();
    }
    if (gid < N) rowptr[gid] = s[t] - v;
    if (t == 1023) bsum[blockIdx.x] = s[1023];
}

__global__ void k_scan_top(int* __restrict__ bsum, int* __restrict__ rowptr_last, int nb) {
    if (threadIdx.x == 0 && blockIdx.x == 0) {
        int run = 0;
        for (int i = 0; i < nb; ++i) { int v = bsum[i]; bsum[i] = run; run += v; }
        *rowptr_last = run;
    }
}

__global__ void k_scan_add(int* __restrict__ rowptr, const int* __restrict__ bsum, int N) {
    int gid = blockIdx.x * blockDim.x + threadIdx.x;
    if (gid < N) rowptr[gid] += bsum[gid >> 10];
}

__global__ void k_scatter(const int* __restrict__ src, const int* __restrict__ dst,
                          const int* __restrict__ rowptr, int* __restrict__ fill,
                          const float* __restrict__ dis,
                          int2* __restrict__ emeta, int E) {
    int e = blockIdx.x * blockDim.x + threadIdx.x;
    if (e >= E) return;
    int d = dst[e], s = src[e];
    int slot = rowptr[d] + atomicAdd(&fill[d], 1);
    emeta[slot] = make_int2(s, __float_as_int(dis[s] * dis[d]));
}

// X (B,WIN,N) f32 -> g0 [n][w][b] f32
__global__ void k_xpose(const float* __restrict__ X, float* __restrict__ h0, int N) {
    long long tid = (long long)blockIdx.x * blockDim.x + threadIdx.x;
    if (tid >= (long long)N * 20) return;
    int n = (int)(tid / 20), r = (int)(tid % 20);
    int b = r & 3, w = r >> 2;
    h0[tid] = X[(size_t)(b * 5 + w) * N + n];
}

// ---------------- layer-0 propagation (f32, deg-balanced order) ----------------
__global__ void k_spmm20(const int* __restrict__ nodeof, const int* __restrict__ rowptr,
                         const int2* __restrict__ emeta,
                         const float* __restrict__ hin, float* __restrict__ hout, int N) {
    long long tid = (long long)blockIdx.x * blockDim.x + threadIdx.x;
    if (tid >= (long long)N * 5) return;
    int n = nodeof[(int)(tid / 5)];
    int w = (int)(tid % 5);
    const float4* hin4 = (const float4*)hin;
    float ax = 0.f, ay = 0.f, az = 0.f, aw = 0.f;
    float bx = 0.f, by = 0.f, bz = 0.f, bw = 0.f;
    int j = rowptr[n], j1 = rowptr[n + 1];
    for (; j + 1 < j1; j += 2) {
        int2 m0 = emeta[j], m1 = emeta[j + 1];
        float4 g0 = hin4[(size_t)m0.x * 5 + w];
        float4 g1 = hin4[(size_t)m1.x * 5 + w];
        float w0 = __int_as_float(m0.y), w1 = __int_as_float(m1.y);
        ax += w0 * g0.x; ay += w0 * g0.y; az += w0 * g0.z; aw += w0 * g0.w;
        bx += w1 * g1.x; by += w1 * g1.y; bz += w1 * g1.z; bw += w1 * g1.w;
    }
    if (j < j1) {
        int2 m = emeta[j];
        float4 g = hin4[(size_t)m.x * 5 + w];
        float wt = __int_as_float(m.y);
        ax += wt * g.x; ay += wt * g.y; az += wt * g.z; aw += wt * g.w;
    }
    float4 o; o.x = ax + bx; o.y = ay + by; o.z = az + bz; o.w = aw + bw;
    ((float4*)hout)[(size_t)n * 5 + w] = o;
}

// ---------------- layer-0 combine ----------------
__global__ __launch_bounds__(256) void k_comb20(const float* __restrict__ g0,
                                                const float* __restrict__ g1,
                                                const float* __restrict__ g2,
                                                const float* __restrict__ g3,
                                                const float* __restrict__ W0,
                                                const float* __restrict__ bias,
                                                uint2* __restrict__ hout, int N) {
    __shared__ float4 ws[160];   // (4,5,32) = 640 floats
    int t = threadIdx.x;
    if (t < 160) ws[t] = ((const float4*)W0)[t];
    __syncthreads();
    long long tid = (long long)blockIdx.x * 256 + t;
    int n = (int)(tid >> 5);
    if (n >= N) return;
    int lane = (int)tid & 31, b = lane >> 3, q = lane & 7;
    float a0 = 0.f, a1 = 0.f, a2 = 0.f, a3 = 0.f;
    const float* gs[4] = {g0, g1, g2, g3};
#pragma unroll
    for (int k = 0; k < 4; ++k) {
        const float* g = gs[k];
#pragma unroll
        for (int w = 0; w < 5; ++w) {
            float hv = g[(size_t)n * 20 + w * 4 + b];
            float4 wv = ws[k * 40 + w * 8 + q];
            a0 += hv * wv.x; a1 += hv * wv.y; a2 += hv * wv.z; a3 += hv * wv.w;
        }
    }
    float4 b4 = ((const float4*)bias)[q];
    float4 v4;
    v4.x = tanhf(a0 + b4.x); v4.y = tanhf(a1 + b4.y);
    v4.z = tanhf(a2 + b4.z); v4.w = tanhf(a3 + b4.w);
    hout[(size_t)n * 32 + lane] = f4_to_h4(v4);
}

// ---------------- gather core: 32 lanes/node, uint2 (8 B) loads ----------------
template <int U>
__device__ __forceinline__ float4 gather32(const int* __restrict__ rowptr,
                                           const int2* __restrict__ emeta,
                                           const uint2* __restrict__ hin,
                                           int n, int lane) {
    float a0 = 0.f, a1 = 0.f, a2 = 0.f, a3 = 0.f;
    float b0 = 0.f, b1 = 0.f, b2 = 0.f, b3 = 0.f;
    int j = rowptr[n], j1 = rowptr[n + 1];
    for (; j + U - 1 < j1; j += U) {
        int2  m[U];
        uint2 u[U];
#pragma unroll
        for (int k = 0; k < U; ++k) m[k] = emeta[j + k];
#pragma unroll
        for (int k = 0; k < U; ++k) u[k] = hin[(size_t)m[k].x * 32 + lane];
#pragma unroll
        for (int k = 0; k < U; ++k) {
            float w = __int_as_float(m[k].y);
            float4 g = h4_to_f4(u[k]);
            if (k & 1) { b0 += w * g.x; b1 += w * g.y; b2 += w * g.z; b3 += w * g.w; }
            else       { a0 += w * g.x; a1 += w * g.y; a2 += w * g.z; a3 += w * g.w; }
        }
    }
    for (; j < j1; ++j) {
        int2 m = emeta[j];
        float w = __int_as_float(m.y);
        float4 g = h4_to_f4(hin[(size_t)m.x * 32 + lane]);
        a0 += w * g.x; a1 += w * g.y; a2 += w * g.z; a3 += w * g.w;
    }
    return make_float4(a0 + b0, a1 + b1, a2 + b2, a3 + b3);
}

// ---------------- LEAN hop, deg-balanced: h_out[n] = (A * h_in)[n], n = nodeof[i] ----------------
__global__ __launch_bounds__(256) void k_hop(const int* __restrict__ nodeof,
                                             const int* __restrict__ rowptr,
                                             const int2* __restrict__ emeta,
                                             const uint2* __restrict__ hin,
                                             uint2* __restrict__ hout, int N) {
    int t = threadIdx.x;
    int nl = t >> 5, lane = t & 31;
    int i = blockIdx.x * 8 + nl;
    if (i >= N) return;
    int n = nodeof[i];
    float4 av = gather32<4>(rowptr, emeta, hin, n, lane);
    hout[(size_t)n * 32 + lane] = f4_to_h4(av);
}

// ---------------- MFMA combine (round-14 verified) ----------------
template <int MODE>
__global__ __launch_bounds__(256) void k_comb_mfma(const f16* __restrict__ h0,
                                                   const f16* __restrict__ h1,
                                                   const f16* __restrict__ h2,
                                                   const f16* __restrict__ h3,
                                                   const float* __restrict__ W,
                                                   const float* __restrict__ bias,
                                                   f16* __restrict__ hout,
                                                   float* __restrict__ out_h,
                                                   const float* __restrict__ Wr,
                                                   const float* __restrict__ br,
                                                   float* __restrict__ pred, int N) {
    __shared__ float wsh[4096];          // (4,32,32) f32 W, 16 KB
    int t = threadIdx.x;
#pragma unroll
    for (int i = 0; i < 16; ++i) wsh[t + i * 256] = W[t + i * 256];
    __syncthreads();

    int lane = t & 63;
    int wid  = t >> 6;
    int lrow = lane & 15;
    int kgrp = lane >> 4;

    f16x8 bf[4][2];
#pragma unroll
    for (int kk = 0; kk < 4; ++kk)
#pragma unroll
        for (int oc = 0; oc < 2; ++oc)
#pragma unroll
            for (int j = 0; j < 8; ++j)
                bf[kk][oc][j] = (f16)wsh[(kk * 32 + kgrp * 8 + j) * 32 + oc * 16 + lrow];

    float blo = bias[lrow], bhi = bias[16 + lrow];
    float wrlo = 0.f, wrhi = 0.f, br0 = 0.f;
    if (MODE == 2) { wrlo = Wr[lrow]; wrhi = Wr[16 + lrow]; br0 = br[0]; }

    int R = N * 4;
    int ntiles = (R + 15) >> 4;
    int nwaves = gridDim.x * 4;
    for (int tile = blockIdx.x * 4 + wid; tile < ntiles; tile += nwaves) {
        int arow = tile * 16 + lrow;
        if (arow >= R) arow = R - 1;
        size_t abase = (size_t)arow * 32 + kgrp * 8;
        f16x8 a0 = *(const f16x8*)(h0 + abase);
        f16x8 a1 = *(const f16x8*)(h1 + abase);
        f16x8 a2 = *(const f16x8*)(h2 + abase);
        f16x8 a3 = *(const f16x8*)(h3 + abase);

        f32x4 acc0 = {0.f, 0.f, 0.f, 0.f};
        f32x4 acc1 = {0.f, 0.f, 0.f, 0.f};
        acc0 = __builtin_amdgcn_mfma_f32_16x16x32_f16(a0, bf[0][0], acc0, 0, 0, 0);
        acc0 = __builtin_amdgcn_mfma_f32_16x16x32_f16(a1, bf[1][0], acc0, 0, 0, 0);
        acc0 = __builtin_amdgcn_mfma_f32_16x16x32_f16(a2, bf[2][0], acc0, 0, 0, 0);
        acc0 = __builtin_amdgcn_mfma_f32_16x16x32_f16(a3, bf[3][0], acc0, 0, 0, 0);
        acc1 = __builtin_amdgcn_mfma_f32_16x16x32_f16(a0, bf[0][1], acc1, 0, 0, 0);
        acc1 = __builtin_amdgcn_mfma_f32_16x16x32_f16(a1, bf[1][1], acc1, 0, 0, 0);
        acc1 = __builtin_amdgcn_mfma_f32_16x16x32_f16(a2, bf[2][1], acc1, 0, 0, 0);
        acc1 = __builtin_amdgcn_mfma_f32_16x16x32_f16(a3, bf[3][1], acc1, 0, 0, 0);

#pragma unroll
        for (int reg = 0; reg < 4; ++reg) {
            int orow = tile * 16 + kgrp * 4 + reg;
            float v0 = tanhf(acc0[reg] + blo);
            float v1 = tanhf(acc1[reg] + bhi);
            if (MODE == 1) {
                if (orow < R) {
                    hout[(size_t)orow * 32 + lrow]      = (f16)v0;
                    hout[(size_t)orow * 32 + 16 + lrow] = (f16)v1;
                }
            } else {
                float p = v0 * wrlo + v1 * wrhi;
                p += __shfl_xor(p, 1);
                p += __shfl_xor(p, 2);
                p += __shfl_xor(p, 4);
                p += __shfl_xor(p, 8);
                if (orow < R) {
                    int nn = orow >> 2, bb = orow & 3;
                    out_h[((size_t)bb * N + nn) * 32 + lrow]      = v0;
                    out_h[((size_t)bb * N + nn) * 32 + 16 + lrow] = v1;
                    if (lrow == 0) pred[(size_t)bb * N + nn] = p + br0;
                }
            }
        }
    }
}

// ---------------- driver ----------------

extern "C" void kernel_launch(void* const* d_in, const int* in_sizes, int n_in,
                              void* d_out, int out_size, void* d_ws, size_t ws_size,
                              hipStream_t stream) {
    const float* X  = (const float*)d_in[0];
    const int*   ei = (const int*)d_in[1];
    const float* W0 = (const float*)d_in[2];
    const float* b0 = (const float*)d_in[3];
    const float* W1 = (const float*)d_in[4];
    const float* b1 = (const float*)d_in[5];
    const float* W2 = (const float*)d_in[6];
    const float* b2 = (const float*)d_in[7];
    const float* Wr = (const float*)d_in[8];
    const float* br = (const float*)d_in[9];

    const int N = in_sizes[0] / 20;
    const int E = in_sizes[1] / 2;
    const int* src = ei;
    const int* dst = ei + E;
    const int nscan = (N + 1023) / 1024;

    char* ws = (char*)d_ws;
    size_t off = 0;
    auto take = [&](size_t bytes) -> char* {
        char* p = ws + off;
        off = (off + bytes + 255) & ~(size_t)255;
        return p;
    };
    const size_t HBYTES = (size_t)N * 128 * 2;   // fp16 node table (12.8 MB)
    const size_t GBYTES = (size_t)N * 20 * 4;    // layer-0 f32 table (4 MB)
    // contiguous zero region: deg(N) fill(N) hfill(NBIN) hist(NBIN)
    int*   ibuf   = (int*)  take(((size_t)2 * N + 2 * NBIN) * 4);
    int*   deg    = ibuf;
    int*   fill   = ibuf + N;
    int*   hfill  = ibuf + 2 * N;
    int*   hist   = ibuf + 2 * N + NBIN;
    int*   hstart = (int*)  take((size_t)NBIN * 4);
    int*   nodeof = (int*)  take((size_t)N * 4);
    int*   rowptr = (int*)  take(((size_t)N + 1) * 4);
    float* dis    = (float*)take((size_t)N * 4);
    int*   bsum   = (int*)  take((size_t)(nscan + 1) * 4);
    int2*  emeta  = (int2*) take((size_t)E * 8);
    uint2* hA     = (uint2*)take(HBYTES);
    uint2* hB     = (uint2*)take(HBYTES);
    uint2* hC     = (uint2*)take(HBYTES);
    uint2* hD     = (uint2*)take(HBYTES);
    float* g0     = (float*)take(GBYTES);
    float* g1     = (float*)take(GBYTES);
    float* g2     = (float*)take(GBYTES);
    float* g3     = (float*)take(GBYTES);
    if (ws_size < off) return;

    dim3 wg(WG);
    auto nb = [](long long total) { return dim3((unsigned)((total + WG - 1) / WG)); };
    dim3 nb8((unsigned)((N + 7) / 8));     // hop: 8 nodes/block

    // ---- graph/normalization setup + deg-sort permutation ----
    k_zero<<<nb(2LL * N + 2 * NBIN), wg, 0, stream>>>(ibuf, 2 * N + 2 * NBIN);
    k_count<<<nb(E), wg, 0, stream>>>(dst, deg, E);
    k_dis<<<nb(N), wg, 0, stream>>>(deg, dis, N);
    k_hist<<<nb(N), wg, 0, stream>>>(deg, hist, N);
    k_scan_hist<<<dim3(1), dim3(NBIN), 0, stream>>>(hist, hstart);
    k_place<<<nb(N), wg, 0, stream>>>(deg, hstart, hfill, nodeof, N);
    k_scan_blk<<<dim3(nscan), dim3(1024), 0, stream>>>(deg, rowptr, bsum, N);
    k_scan_top<<<dim3(1), dim3(64), 0, stream>>>(bsum, rowptr + N, nscan);
    k_scan_add<<<nb(N), wg, 0, stream>>>(rowptr, bsum, N);
    k_scatter<<<nb(E), wg, 0, stream>>>(src, dst, rowptr, fill, dis, emeta, E);

    // ---- h0 = X^T -> [n][w][4b] ----
    k_xpose<<<nb((long long)N * 20), wg, 0, stream>>>(X, g0, N);

    float* out_pred = (float*)d_out;
    float* out_h    = (float*)d_out + (size_t)4 * N;

    // ---- layer 0 (5 -> 32): 3 deg-balanced f32 hops + combine ----
    k_spmm20<<<nb((long long)N * 5), wg, 0, stream>>>(nodeof, rowptr, emeta, g0, g1, N);
    k_spmm20<<<nb((long long)N * 5), wg, 0, stream>>>(nodeof, rowptr, emeta, g1, g2, N);
    k_spmm20<<<nb((long long)N * 5), wg, 0, stream>>>(nodeof, rowptr, emeta, g2, g3, N);
    k_comb20<<<nb((long long)N * 32), wg, 0, stream>>>(g0, g1, g2, g3, W0, b0, hA, N);

    // ---- layer 1 (32 -> 32): 3 deg-balanced hops + MFMA combine ----
    k_hop<<<nb8, wg, 0, stream>>>(nodeof, rowptr, emeta, hA, hB, N);
    k_hop<<<nb8, wg, 0, stream>>>(nodeof, rowptr, emeta, hB, hC, N);
    k_hop<<<nb8, wg, 0, stream>>>(nodeof, rowptr, emeta, hC, hD, N);
    k_comb_mfma<1><<<dim3(1024), wg, 0, stream>>>((const f16*)hA, (const f16*)hB,
                                                  (const f16*)hC, (const f16*)hD,
                                                  W1, b1, (f16*)hA,
                                                  nullptr, nullptr, nullptr, nullptr, N);

    // ---- layer 2 (32 -> 32): 3 deg-balanced hops + MFMA combine(out) ----
    k_hop<<<nb8, wg, 0, stream>>>(nodeof, rowptr, emeta, hA, hB, N);
    k_hop<<<nb8, wg, 0, stream>>>(nodeof, rowptr, emeta, hB, hC, N);
    k_hop<<<nb8, wg, 0, stream>>>(nodeof, rowptr, emeta, hC, hD, N);
    k_comb_mfma<2><<<dim3(1024), wg, 0, stream>>>((const f16*)hA, (const f16*)hB,
                                                  (const f16*)hC, (const f16*)hD,
                                                  W2, b2, nullptr,
                                                  out_h, Wr, br, out_pred, N);
}

// Round 16
// 376.976 us; speedup vs baseline: 1.7234x; 1.7234x over previous
//
#include <hip/hip_runtime.h>
#include <hip/hip_fp16.h>

#define WG 256

typedef _Float16 f16;
typedef f16 f16x8 __attribute__((ext_vector_type(8)));
typedef float f32x4 __attribute__((ext_vector_type(4)));

// ---- fp16 helpers: 4 channels <-> uint2 ----
__device__ __forceinline__ float4 h4_to_f4(uint2 u) {
    union { unsigned int x; __half2 h; } a, b;
    a.x = u.x; b.x = u.y;
    float2 f0 = __half22float2(a.h);
    float2 f1 = __half22float2(b.h);
    return make_float4(f0.x, f0.y, f1.x, f1.y);
}
__device__ __forceinline__ uint2 f4_to_h4(float4 v) {
    union { unsigned int x; __half2 h; } a, b;
    a.h = __floats2half2_rn(v.x, v.y);
    b.h = __floats2half2_rn(v.z, v.w);
    return make_uint2(a.x, b.x);
}

// ---------------- setup kernels ----------------

__global__ void k_zero2(int* __restrict__ a, int* __restrict__ b, int n) {
    int i = blockIdx.x * blockDim.x + threadIdx.x;
    if (i < n) { a[i] = 0; b[i] = 0; }
}

__global__ void k_count(const int* __restrict__ dst, int* __restrict__ deg, int E) {
    int e = blockIdx.x * blockDim.x + threadIdx.x;
    if (e < E) atomicAdd(&deg[dst[e]], 1);
}

__global__ void k_dis(const int* __restrict__ deg, float* __restrict__ dis, int N) {
    int n = blockIdx.x * blockDim.x + threadIdx.x;
    if (n < N) {
        int d = deg[n];
        dis[n] = (d > 0) ? rsqrtf((float)d) : 0.0f;
    }
}

// ---- hierarchical scan ----
__global__ __launch_bounds__(1024) void k_scan_blk(const int* __restrict__ deg,
                                                   int* __restrict__ rowptr,
                                                   int* __restrict__ bsum, int N) {
    __shared__ int s[1024];
    int t = threadIdx.x;
    int gid = blockIdx.x * 1024 + t;
    int v = (gid < N) ? deg[gid] : 0;
    s[t] = v;
    __syncthreads();
    for (int off = 1; off < 1024; off <<= 1) {
        int u = (t >= off) ? s[t - off] : 0;
        __syncthreads();
        s[t] += u;
        __syncthreads();
    }
    if (gid < N) rowptr[gid] = s[t] - v;
    if (t == 1023) bsum[blockIdx.x] = s[1023];
}

__global__ void k_scan_top(int* __restrict__ bsum, int* __restrict__ rowptr_last, int nb) {
    if (threadIdx.x == 0 && blockIdx.x == 0) {
        int run = 0;
        for (int i = 0; i < nb; ++i) { int v = bsum[i]; bsum[i] = run; run += v; }
        *rowptr_last = run;
    }
}

__global__ void k_scan_add(int* __restrict__ rowptr, const int* __restrict__ bsum, int N) {
    int gid = blockIdx.x * blockDim.x + threadIdx.x;
    if (gid < N) rowptr[gid] += bsum[gid >> 10];
}

__global__ void k_scatter(const int* __restrict__ src, const int* __restrict__ dst,
                          const int* __restrict__ rowptr, int* __restrict__ fill,
                          const float* __restrict__ dis,
                          int2* __restrict__ emeta, int E) {
    int e = blockIdx.x * blockDim.x + threadIdx.x;
    if (e >= E) return;
    int d = dst[e], s = src[e];
    int slot = rowptr[d] + atomicAdd(&fill[d], 1);
    emeta[slot] = make_int2(s, __float_as_int(dis[s] * dis[d]));
}

// X (B,WIN,N) f32 -> g0 [n][w][b] f32
__global__ void k_xpose(const float* __restrict__ X, float* __restrict__ h0, int N) {
    long long tid = (long long)blockIdx.x * blockDim.x + threadIdx.x;
    if (tid >= (long long)N * 20) return;
    int n = (int)(tid / 20), r = (int)(tid % 20);
    int b = r & 3, w = r >> 2;
    h0[tid] = X[(size_t)(b * 5 + w) * N + n];
}

// ---------------- layer-0 propagation (f32, 4 MB table: L2-resident) ----------------
__global__ void k_spmm20(const int* __restrict__ rowptr, const int2* __restrict__ emeta,
                         const float* __restrict__ hin, float* __restrict__ hout, int N) {
    long long tid = (long long)blockIdx.x * blockDim.x + threadIdx.x;
    if (tid >= (long long)N * 5) return;
    int n = (int)(tid / 5), w = (int)(tid % 5);
    const float4* hin4 = (const float4*)hin;
    float ax = 0.f, ay = 0.f, az = 0.f, aw = 0.f;
    float bx = 0.f, by = 0.f, bz = 0.f, bw = 0.f;
    int j = rowptr[n], j1 = rowptr[n + 1];
    for (; j + 1 < j1; j += 2) {
        int2 m0 = emeta[j], m1 = emeta[j + 1];
        float4 g0 = hin4[(size_t)m0.x * 5 + w];
        float4 g1 = hin4[(size_t)m1.x * 5 + w];
        float w0 = __int_as_float(m0.y), w1 = __int_as_float(m1.y);
        ax += w0 * g0.x; ay += w0 * g0.y; az += w0 * g0.z; aw += w0 * g0.w;
        bx += w1 * g1.x; by += w1 * g1.y; bz += w1 * g1.z; bw += w1 * g1.w;
    }
    if (j < j1) {
        int2 m = emeta[j];
        float4 g = hin4[(size_t)m.x * 5 + w];
        float wt = __int_as_float(m.y);
        ax += wt * g.x; ay += wt * g.y; az += wt * g.z; aw += wt * g.w;
    }
    float4 o; o.x = ax + bx; o.y = ay + by; o.z = az + bz; o.w = aw + bw;
    ((float4*)hout)[(size_t)n * 5 + w] = o;
}

// ---------------- layer-0 combine: v = tanh(sum_{k,w} g_k[n][w][b] * W0[k][w][o] + b0) ----------------
__global__ __launch_bounds__(256) void k_comb20(const float* __restrict__ g0,
                                                const float* __restrict__ g1,
                                                const float* __restrict__ g2,
                                                const float* __restrict__ g3,
                                                const float* __restrict__ W0,
                                                const float* __restrict__ bias,
                                                uint2* __restrict__ hout, int N) {
    __shared__ float4 ws[160];   // (4,5,32) = 640 floats
    int t = threadIdx.x;
    if (t < 160) ws[t] = ((const float4*)W0)[t];
    __syncthreads();
    long long tid = (long long)blockIdx.x * 256 + t;
    int n = (int)(tid >> 5);
    if (n >= N) return;
    int lane = (int)tid & 31, b = lane >> 3, q = lane & 7;
    float a0 = 0.f, a1 = 0.f, a2 = 0.f, a3 = 0.f;
    const float* gs[4] = {g0, g1, g2, g3};
#pragma unroll
    for (int k = 0; k < 4; ++k) {
        const float* g = gs[k];
#pragma unroll
        for (int w = 0; w < 5; ++w) {
            float hv = g[(size_t)n * 20 + w * 4 + b];
            float4 wv = ws[k * 40 + w * 8 + q];
            a0 += hv * wv.x; a1 += hv * wv.y; a2 += hv * wv.z; a3 += hv * wv.w;
        }
    }
    float4 b4 = ((const float4*)bias)[q];
    float4 v4;
    v4.x = tanhf(a0 + b4.x); v4.y = tanhf(a1 + b4.y);
    v4.z = tanhf(a2 + b4.z); v4.w = tanhf(a3 + b4.w);
    hout[(size_t)n * 32 + lane] = f4_to_h4(v4);
}

// ---------------- gather core: 32 lanes/node, uint2 (8 B) loads ----------------
template <int U>
__device__ __forceinline__ float4 gather32(const int* __restrict__ rowptr,
                                           const int2* __restrict__ emeta,
                                           const uint2* __restrict__ hin,
                                           int n, int lane) {
    float a0 = 0.f, a1 = 0.f, a2 = 0.f, a3 = 0.f;
    float b0 = 0.f, b1 = 0.f, b2 = 0.f, b3 = 0.f;
    int j = rowptr[n], j1 = rowptr[n + 1];
    for (; j + U - 1 < j1; j += U) {
        int2  m[U];
        uint2 u[U];
#pragma unroll
        for (int k = 0; k < U; ++k) m[k] = emeta[j + k];
#pragma unroll
        for (int k = 0; k < U; ++k) u[k] = hin[(size_t)m[k].x * 32 + lane];
#pragma unroll
        for (int k = 0; k < U; ++k) {
            float w = __int_as_float(m[k].y);
            float4 g = h4_to_f4(u[k]);
            if (k & 1) { b0 += w * g.x; b1 += w * g.y; b2 += w * g.z; b3 += w * g.w; }
            else       { a0 += w * g.x; a1 += w * g.y; a2 += w * g.z; a3 += w * g.w; }
        }
    }
    for (; j < j1; ++j) {
        int2 m = emeta[j];
        float w = __int_as_float(m.y);
        float4 g = h4_to_f4(hin[(size_t)m.x * 32 + lane]);
        a0 += w * g.x; a1 += w * g.y; a2 += w * g.z; a3 += w * g.w;
    }
    return make_float4(a0 + b0, a1 + b1, a2 + b2, a3 + b3);
}

// ---------------- LEAN hop: h_out = A * h_in (fp16) ----------------
__global__ __launch_bounds__(256) void k_hop(const int* __restrict__ rowptr,
                                             const int2* __restrict__ emeta,
                                             const uint2* __restrict__ hin,
                                             uint2* __restrict__ hout, int N) {
    int t = threadIdx.x;
    int nl = t >> 5, lane = t & 31;
    int n = blockIdx.x * 8 + nl;
    if (n >= N) return;
    float4 av = gather32<4>(rowptr, emeta, hin, n, lane);
    hout[(size_t)n * 32 + lane] = f4_to_h4(av);
}

// ---------------- MFMA combine: rows (n*4+b) x K=128 @ W(128x32) ----------------
// A: fp16 tables h0..h3, row-major [r][32]; fragment: row = lane&15,
// k = (lane>>4)*8 + j (contiguous 8 = one 16B load per table).
// B: W[k][o] fp16 fragments: col = lane&15, k = (lane>>4)*8 + j (built once from LDS).
// C/D (m89-verified, dtype-independent): col = lane&15, row = (lane>>4)*4 + reg.
// MODE 1: hout fp16 [r][32] (in-place over h0 safe: wave reads its tile before storing)
// MODE 2: out_h f32 [(b*N+n)][32] + pred[b*N+n]
template <int MODE>
__global__ __launch_bounds__(256) void k_comb_mfma(const f16* __restrict__ h0,
                                                   const f16* __restrict__ h1,
                                                   const f16* __restrict__ h2,
                                                   const f16* __restrict__ h3,
                                                   const float* __restrict__ W,
                                                   const float* __restrict__ bias,
                                                   f16* __restrict__ hout,
                                                   float* __restrict__ out_h,
                                                   const float* __restrict__ Wr,
                                                   const float* __restrict__ br,
                                                   float* __restrict__ pred, int N) {
    __shared__ float wsh[4096];          // (4,32,32) f32 W, 16 KB
    int t = threadIdx.x;
#pragma unroll
    for (int i = 0; i < 16; ++i) wsh[t + i * 256] = W[t + i * 256];
    __syncthreads();

    int lane = t & 63;
    int wid  = t >> 6;                   // wave 0..3
    int lrow = lane & 15;                // A-row within tile / C-col
    int kgrp = lane >> 4;                // 0..3

    // B fragments: bf[kk][oc][j] = W[kk*32 + kgrp*8 + j][oc*16 + lrow]
    f16x8 bf[4][2];
#pragma unroll
    for (int kk = 0; kk < 4; ++kk)
#pragma unroll
        for (int oc = 0; oc < 2; ++oc)
#pragma unroll
            for (int j = 0; j < 8; ++j)
                bf[kk][oc][j] = (f16)wsh[(kk * 32 + kgrp * 8 + j) * 32 + oc * 16 + lrow];

    float blo = bias[lrow], bhi = bias[16 + lrow];
    float wrlo = 0.f, wrhi = 0.f, br0 = 0.f;
    if (MODE == 2) { wrlo = Wr[lrow]; wrhi = Wr[16 + lrow]; br0 = br[0]; }

    int R = N * 4;
    int ntiles = (R + 15) >> 4;
    int nwaves = gridDim.x * 4;
    for (int tile = blockIdx.x * 4 + wid; tile < ntiles; tile += nwaves) {
        int arow = tile * 16 + lrow;
        if (arow >= R) arow = R - 1;             // tail clamp (loads only)
        size_t abase = (size_t)arow * 32 + kgrp * 8;
        f16x8 a0 = *(const f16x8*)(h0 + abase);
        f16x8 a1 = *(const f16x8*)(h1 + abase);
        f16x8 a2 = *(const f16x8*)(h2 + abase);
        f16x8 a3 = *(const f16x8*)(h3 + abase);

        f32x4 acc0 = {0.f, 0.f, 0.f, 0.f};
        f32x4 acc1 = {0.f, 0.f, 0.f, 0.f};
        acc0 = __builtin_amdgcn_mfma_f32_16x16x32_f16(a0, bf[0][0], acc0, 0, 0, 0);
        acc0 = __builtin_amdgcn_mfma_f32_16x16x32_f16(a1, bf[1][0], acc0, 0, 0, 0);
        acc0 = __builtin_amdgcn_mfma_f32_16x16x32_f16(a2, bf[2][0], acc0, 0, 0, 0);
        acc0 = __builtin_amdgcn_mfma_f32_16x16x32_f16(a3, bf[3][0], acc0, 0, 0, 0);
        acc1 = __builtin_amdgcn_mfma_f32_16x16x32_f16(a0, bf[0][1], acc1, 0, 0, 0);
        acc1 = __builtin_amdgcn_mfma_f32_16x16x32_f16(a1, bf[1][1], acc1, 0, 0, 0);
        acc1 = __builtin_amdgcn_mfma_f32_16x16x32_f16(a2, bf[2][1], acc1, 0, 0, 0);
        acc1 = __builtin_amdgcn_mfma_f32_16x16x32_f16(a3, bf[3][1], acc1, 0, 0, 0);

#pragma unroll
        for (int reg = 0; reg < 4; ++reg) {
            int orow = tile * 16 + kgrp * 4 + reg;
            float v0 = tanhf(acc0[reg] + blo);
            float v1 = tanhf(acc1[reg] + bhi);
            if (MODE == 1) {
                if (orow < R) {
                    hout[(size_t)orow * 32 + lrow]      = (f16)v0;
                    hout[(size_t)orow * 32 + 16 + lrow] = (f16)v1;
                }
            } else {
                float p = v0 * wrlo + v1 * wrhi;
                p += __shfl_xor(p, 1);
                p += __shfl_xor(p, 2);
                p += __shfl_xor(p, 4);
                p += __shfl_xor(p, 8);
                if (orow < R) {
                    int nn = orow >> 2, bb = orow & 3;
                    out_h[((size_t)bb * N + nn) * 32 + lrow]      = v0;
                    out_h[((size_t)bb * N + nn) * 32 + 16 + lrow] = v1;
                    if (lrow == 0) pred[(size_t)bb * N + nn] = p + br0;
                }
            }
        }
    }
}

// ---------------- driver ----------------

extern "C" void kernel_launch(void* const* d_in, const int* in_sizes, int n_in,
                              void* d_out, int out_size, void* d_ws, size_t ws_size,
                              hipStream_t stream) {
    const float* X  = (const float*)d_in[0];
    const int*   ei = (const int*)d_in[1];
    const float* W0 = (const float*)d_in[2];
    const float* b0 = (const float*)d_in[3];
    const float* W1 = (const float*)d_in[4];
    const float* b1 = (const float*)d_in[5];
    const float* W2 = (const float*)d_in[6];
    const float* b2 = (const float*)d_in[7];
    const float* Wr = (const float*)d_in[8];
    const float* br = (const float*)d_in[9];

    const int N = in_sizes[0] / 20;
    const int E = in_sizes[1] / 2;
    const int* src = ei;
    const int* dst = ei + E;
    const int nscan = (N + 1023) / 1024;

    char* ws = (char*)d_ws;
    size_t off = 0;
    auto take = [&](size_t bytes) -> char* {
        char* p = ws + off;
        off = (off + bytes + 255) & ~(size_t)255;
        return p;
    };
    const size_t HBYTES = (size_t)N * 128 * 2;   // fp16 node table (12.8 MB)
    const size_t GBYTES = (size_t)N * 20 * 4;    // layer-0 f32 table (4 MB)
    int*   deg    = (int*)  take((size_t)N * 4);
    int*   fill   = (int*)  take((size_t)N * 4);
    int*   rowptr = (int*)  take(((size_t)N + 1) * 4);
    float* dis    = (float*)take((size_t)N * 4);
    int*   bsum   = (int*)  take((size_t)(nscan + 1) * 4);
    int2*  emeta  = (int2*) take((size_t)E * 8);
    uint2* hA     = (uint2*)take(HBYTES);
    uint2* hB     = (uint2*)take(HBYTES);
    uint2* hC     = (uint2*)take(HBYTES);
    uint2* hD     = (uint2*)take(HBYTES);
    float* g0     = (float*)take(GBYTES);
    float* g1     = (float*)take(GBYTES);
    float* g2     = (float*)take(GBYTES);
    float* g3     = (float*)take(GBYTES);
    if (ws_size < off) return;

    dim3 wg(WG);
    auto nb = [](long long total) { return dim3((unsigned)((total + WG - 1) / WG)); };
    dim3 nb8((unsigned)((N + 7) / 8));     // hop: 8 nodes/block

    // ---- graph/normalization setup ----
    k_zero2<<<nb(N), wg, 0, stream>>>(deg, fill, N);
    k_count<<<nb(E), wg, 0, stream>>>(dst, deg, E);
    k_dis<<<nb(N), wg, 0, stream>>>(deg, dis, N);
    k_scan_blk<<<dim3(nscan), dim3(1024), 0, stream>>>(deg, rowptr, bsum, N);
    k_scan_top<<<dim3(1), dim3(64), 0, stream>>>(bsum, rowptr + N, nscan);
    k_scan_add<<<nb(N), wg, 0, stream>>>(rowptr, bsum, N);
    k_scatter<<<nb(E), wg, 0, stream>>>(src, dst, rowptr, fill, dis, emeta, E);

    // ---- h0 = X^T -> [n][w][4b] ----
    k_xpose<<<nb((long long)N * 20), wg, 0, stream>>>(X, g0, N);

    float* out_pred = (float*)d_out;
    float* out_h    = (float*)d_out + (size_t)4 * N;

    // ---- layer 0 (5 -> 32): 3 lean f32 hops + combine ----
    k_spmm20<<<nb((long long)N * 5), wg, 0, stream>>>(rowptr, emeta, g0, g1, N);
    k_spmm20<<<nb((long long)N * 5), wg, 0, stream>>>(rowptr, emeta, g1, g2, N);
    k_spmm20<<<nb((long long)N * 5), wg, 0, stream>>>(rowptr, emeta, g2, g3, N);
    k_comb20<<<nb((long long)N * 32), wg, 0, stream>>>(g0, g1, g2, g3, W0, b0, hA, N);

    // ---- layer 1 (32 -> 32): 3 lean hops + MFMA combine ----
    k_hop<<<nb8, wg, 0, stream>>>(rowptr, emeta, hA, hB, N);
    k_hop<<<nb8, wg, 0, stream>>>(rowptr, emeta, hB, hC, N);
    k_hop<<<nb8, wg, 0, stream>>>(rowptr, emeta, hC, hD, N);
    k_comb_mfma<1><<<dim3(1024), wg, 0, stream>>>((const f16*)hA, (const f16*)hB,
                                                  (const f16*)hC, (const f16*)hD,
                                                  W1, b1, (f16*)hA,
                                                  nullptr, nullptr, nullptr, nullptr, N);

    // ---- layer 2 (32 -> 32): 3 lean hops + MFMA combine(out) ----
    k_hop<<<nb8, wg, 0, stream>>>(rowptr, emeta, hA, hB, N);
    k_hop<<<nb8, wg, 0, stream>>>(rowptr, emeta, hB, hC, N);
    k_hop<<<nb8, wg, 0, stream>>>(rowptr, emeta, hC, hD, N);
    k_comb_mfma<2><<<dim3(1024), wg, 0, stream>>>((const f16*)hA, (const f16*)hB,
                                                  (const f16*)hC, (const f16*)hD,
                                                  W2, b2, nullptr,
                                                  out_h, Wr, br, out_pred, N);
}